// Round 10
// baseline (382.212 us; speedup 1.0000x reference)
//
#include <hip/hip_runtime.h>

// Problem constants
#define V_SZ 32000
#define E_SZ 128
#define H_SZ 32
#define L_SZ 64
#define B_SZ 32
#define M_TOT 2048   // L*B rows
#define K2 64        // 2H
#define NVT 125      // V/256 col-slices
#define NMT 32       // M_TOT/64 row-tiles
#define NPART 250    // sum-exp partials per row (125 xcol x 2 wn)
#define PLD 256      // padded leading dim of Asum2[row][]

typedef __bf16 bf16x8 __attribute__((ext_vector_type(8)));
typedef float f32x4 __attribute__((ext_vector_type(4)));

__device__ __forceinline__ unsigned short f2bf(float f) {
    unsigned int u = __float_as_uint(f);
    u += 0x7FFFu + ((u >> 16) & 1u);   // round-to-nearest-even
    return (unsigned short)(u >> 16);
}

// ---------------------------------------------------------------------------
// Proven helpers (R6/R8): B fragments resident before MFMA; 64x256 tile GEMM.
// C layout: row = wm*32 + m*16 + lg*4 + r, col = wn*128 + n*16 + lr.
// ---------------------------------------------------------------------------
__device__ __forceinline__ void load_bfrag(
    const __bf16* __restrict__ h2oT, int xcol, int wn, int lg, int lr,
    bf16x8 bfr[8][2]) {
    const int colbase = xcol * 256;
#pragma unroll
    for (int n = 0; n < 8; ++n) {
        int col = colbase + wn * 128 + n * 16 + lr;
        const __bf16* bp = h2oT + (size_t)col * K2 + lg * 8;
        bfr[n][0] = *(const bf16x8*)(bp);
        bfr[n][1] = *(const bf16x8*)(bp + 32);
    }
}

__device__ __forceinline__ void tile_gemm(
    const __bf16* __restrict__ hcat, int rowbase, int wm, int lg, int lr,
    const bf16x8 bfr[8][2], f32x4 acc[2][8]) {
    bf16x8 af[2][2];
#pragma unroll
    for (int m = 0; m < 2; ++m) {
        int row = rowbase + wm * 32 + m * 16 + lr;
#pragma unroll
        for (int kh = 0; kh < 2; ++kh)
            af[m][kh] = *(const bf16x8*)(hcat + row * K2 + kh * 32 + lg * 8);
    }
#pragma unroll
    for (int m = 0; m < 2; ++m)
#pragma unroll
        for (int n = 0; n < 8; ++n) acc[m][n] = (f32x4){0.f, 0.f, 0.f, 0.f};
#pragma unroll
    for (int n = 0; n < 8; ++n)
#pragma unroll
        for (int m = 0; m < 2; ++m) {
            acc[m][n] = __builtin_amdgcn_mfma_f32_16x16x32_bf16(af[m][0], bfr[n][0], acc[m][n], 0, 0, 0);
            acc[m][n] = __builtin_amdgcn_mfma_f32_16x16x32_bf16(af[m][1], bfr[n][1], acc[m][n], 0, 0, 0);
        }
}

// ---------------------------------------------------------------------------
// Kernel 1: blocks 0..124  -> transpose+convert h2o -> h2oT (256 rows each)
//           blocks 125..156 -> emb-GEMM into LDS + RNN recurrence
// (unchanged, proven since R6)
// ---------------------------------------------------------------------------
__global__ __launch_bounds__(256) void k_prep_rnn(
    const int* __restrict__ inp, const float* __restrict__ we,
    const float* __restrict__ i2h1, const float* __restrict__ i2h2,
    const float* __restrict__ h2o, const float* __restrict__ bias,
    const float* __restrict__ hinit,
    unsigned short* __restrict__ hcat_u, unsigned short* __restrict__ h2oT_u) {
    const int tid = threadIdx.x;
    const int p = blockIdx.x;
    if (p < 125) {
        const int v = p * 256 + tid;               // [0,32000) exact
        unsigned int* dst = (unsigned int*)(h2oT_u + (size_t)v * K2);
#pragma unroll
        for (int k = 0; k < K2; k += 2) {
            float a = h2o[(size_t)k * V_SZ + v];
            float b = h2o[(size_t)(k + 1) * V_SZ + v];
            dst[k >> 1] = (unsigned int)f2bf(a) | ((unsigned int)f2bf(b) << 16);
        }
        return;
    }
    // ---- emb + RNN block (one direction, 2 batch rows) ----
    const int w2 = p - 125;                        // 0..31
    const int dir = w2 >> 4;
    const int bpair = w2 & 15;
    const float* W = dir ? i2h2 : i2h1;
    __shared__ float Xl[L_SZ * 2 * H_SZ];          // 16 KB: X[t][bb][j]
    {
        const int j = tid & 31, bb = (tid >> 5) & 1, to = tid >> 6;
        const int b = bpair * 2 + bb;
        const float bj = bias[j];
        for (int tt = 0; tt < 16; ++tt) {
            const int t = to * 16 + tt;
            const int idx = inp[t * B_SZ + b];
            const float* er = we + (size_t)idx * E_SZ;
            float acc = bj;
#pragma unroll
            for (int k0 = 0; k0 < E_SZ; k0 += 4) {
                f32x4 e4 = *(const f32x4*)(er + k0);
                acc += e4.x * W[(k0 + 0) * H_SZ + j];
                acc += e4.y * W[(k0 + 1) * H_SZ + j];
                acc += e4.z * W[(k0 + 2) * H_SZ + j];
                acc += e4.w * W[(k0 + 3) * H_SZ + j];
            }
            Xl[(t * 2 + bb) * H_SZ + j] = acc;
        }
    }
    __syncthreads();
    if (tid < 64) {
        const int lane = tid;
        const int bb = lane >> 5;
        const int b = bpair * 2 + bb;
        const int j = lane & 31;
        const int srcbase = lane & 32;
        float wh[H_SZ];
#pragma unroll
        for (int k = 0; k < H_SZ; ++k) wh[k] = W[(E_SZ + k) * H_SZ + j];
        float h = hinit[j];
        for (int step = 0; step < L_SZ; ++step) {
            const int tt = dir ? (L_SZ - 1 - step) : step;
            hcat_u[(tt * B_SZ + b) * K2 + dir * H_SZ + j] = f2bf(h);
            float a0 = Xl[(tt * 2 + bb) * H_SZ + j];
            float a1 = 0.f, a2 = 0.f, a3 = 0.f;
#pragma unroll
            for (int k = 0; k < H_SZ; k += 4) {
                a0 += __shfl(h, srcbase | k, 64) * wh[k];
                a1 += __shfl(h, srcbase | (k + 1), 64) * wh[k + 1];
                a2 += __shfl(h, srcbase | (k + 2), 64) * wh[k + 2];
                a3 += __shfl(h, srcbase | (k + 3), 64) * wh[k + 3];
            }
            float x2 = (a0 + a1) + (a2 + a3);
            float e = __expf(2.f * x2);            // tanh = 1 - 2/(e^{2x}+1)
            h = 1.f - 2.f * __builtin_amdgcn_rcpf(e + 1.f);
        }
    }
}

// ---------------------------------------------------------------------------
// Kernel 2 (pass A): grid (125,4), BARRIER-FREE, zero LDS. Each block loads
// its B fragments once, sweeps 8 row-tiles; per-wave sum-exp partials go
// straight to Asum2[row][xcol*2+wn] (250 partials per row, summed in pass B).
// No __syncthreads -> tile jt+1 loads/MFMAs overlap tile jt's exp/reduce.
// ---------------------------------------------------------------------------
__global__ __launch_bounds__(256) void k_pass_a(
    const __bf16* __restrict__ hcat, const __bf16* __restrict__ h2oT,
    float* __restrict__ Asum2) {
    const int tid = threadIdx.x;
    const int wave = tid >> 6, lane = tid & 63;
    const int wm = wave >> 1, wn = wave & 1;
    const int lg = lane >> 4, lr = lane & 15;
    const int xcol = blockIdx.x;
    const int pcol = xcol * 2 + wn;

    bf16x8 bfr[8][2];
    load_bfrag(h2oT, xcol, wn, lg, lr, bfr);

    for (int jt = 0; jt < 8; ++jt) {
        const int rowbase = (blockIdx.y * 8 + jt) * 64;
        f32x4 acc[2][8];
        tile_gemm(hcat, rowbase, wm, lg, lr, bfr, acc);
        float rs[2][4];
#pragma unroll
        for (int m = 0; m < 2; ++m)
#pragma unroll
            for (int r = 0; r < 4; ++r) {
                float s = 0.f;
#pragma unroll
                for (int n = 0; n < 8; ++n) s += __expf(acc[m][n][r]);
                rs[m][r] = s;
            }
        // reduce over the 16 lr lanes (cols within this wn half)
#pragma unroll
        for (int mask = 1; mask < 16; mask <<= 1)
#pragma unroll
            for (int m = 0; m < 2; ++m)
#pragma unroll
                for (int r = 0; r < 4; ++r)
                    rs[m][r] += __shfl_xor(rs[m][r], mask, 64);
        if (lr == 0) {
#pragma unroll
            for (int m = 0; m < 2; ++m)
#pragma unroll
                for (int r = 0; r < 4; ++r) {
                    const int row = rowbase + wm * 32 + m * 16 + lg * 4 + r;
                    Asum2[(size_t)row * PLD + pcol] = rs[m][r];
                }
        }
    }
}

// ---------------------------------------------------------------------------
// Kernel 3 (pass B + fused lse): per block, (a) reduce 250 partials for each
// of its 64 rows -> lse in LDS, (b) B-resident GEMM recompute, (c) two-chunk
// LDS repack -> coalesced f32x4 stores of logit - lse. grid (125,32).
// ---------------------------------------------------------------------------
__global__ __launch_bounds__(256) void k_pass_b(
    const __bf16* __restrict__ hcat, const __bf16* __restrict__ h2oT,
    const float* __restrict__ Asum2, float* __restrict__ out) {
    const int tid = threadIdx.x;
    const int wave = tid >> 6, lane = tid & 63;
    const int wm = wave >> 1, wn = wave & 1;
    const int lg = lane >> 4, lr = lane & 15;
    const int rowbase = blockIdx.y * 64;
    const int colbase = blockIdx.x * 256;

    // ---- (a) lse for the 64 rows of this tile ----
    __shared__ float part[64][4];
    __shared__ float lse_s[64];
    {
        const int r = tid >> 2, q = tid & 3;
        const int i0 = q * 63;
        const int i1 = (q == 3) ? NPART : (i0 + 63);
        const float* ap = Asum2 + (size_t)(rowbase + r) * PLD;
        float s = 0.f;
        for (int i = i0; i < i1; ++i) s += ap[i];
        part[r][q] = s;
    }
    __syncthreads();
    if (tid < 64)
        lse_s[tid] = logf(part[tid][0] + part[tid][1] + part[tid][2] + part[tid][3]);

    // ---- (b) GEMM recompute (B-resident) ----
    bf16x8 bfr[8][2];
    load_bfrag(h2oT, blockIdx.x, wn, lg, lr, bfr);
    f32x4 acc[2][8];
    tile_gemm(hcat, rowbase, wm, lg, lr, bfr, acc);
    __syncthreads();                   // lse_s ready (and part[] done)
    float lsev[2][4];
#pragma unroll
    for (int m = 0; m < 2; ++m)
#pragma unroll
        for (int r = 0; r < 4; ++r)
            lsev[m][r] = lse_s[wm * 32 + m * 16 + lg * 4 + r];

    // ---- (c) two-chunk LDS repack -> coalesced f32x4 stores ----
    __shared__ float cbuf[32 * 260];   // 33.3 KB; pad 260 breaks conflicts
#pragma unroll
    for (int c = 0; c < 2; ++c) {
        if (c) __syncthreads();        // WAR guard on cbuf reuse
#pragma unroll
        for (int n = 0; n < 8; ++n)
#pragma unroll
            for (int r = 0; r < 4; ++r)
                cbuf[(wm * 16 + lg * 4 + r) * 260 + wn * 128 + n * 16 + lr] =
                    acc[c][n][r] - lsev[c][r];
        __syncthreads();
#pragma unroll
        for (int it = 0; it < 8; ++it) {
            int idx4 = it * 256 + tid;     // float4 index in 32x256 chunk
            int lrow = idx4 >> 6;          // 64 float4 per row
            int col = (idx4 & 63) << 2;
            int grow = rowbase + (lrow >> 4) * 32 + c * 16 + (lrow & 15);
            f32x4 v = *(const f32x4*)&cbuf[lrow * 260 + col];
            *(f32x4*)(out + (size_t)grow * V_SZ + colbase + col) = v;
        }
    }
}

// ---------------------------------------------------------------------------
extern "C" void kernel_launch(void* const* d_in, const int* in_sizes, int n_in,
                              void* d_out, int out_size, void* d_ws, size_t ws_size,
                              hipStream_t stream) {
    (void)in_sizes; (void)n_in; (void)out_size; (void)ws_size;
    const int*   inp   = (const int*)d_in[0];
    const float* we    = (const float*)d_in[1];
    const float* i2h1  = (const float*)d_in[2];
    const float* i2h2  = (const float*)d_in[3];
    const float* h2o   = (const float*)d_in[4];
    const float* bias  = (const float*)d_in[5];
    const float* hinit = (const float*)d_in[6];
    float* out = (float*)d_out;
    char* ws = (char*)d_ws;
    unsigned short* hcat_u = (unsigned short*)(ws);           //  262144 B
    unsigned short* h2oT_u = (unsigned short*)(ws + 262144);  // 4096000 B
    float*          Asum2  = (float*)(ws + 4358144);          // 2097152 B

    k_prep_rnn<<<157, 256, 0, stream>>>(inp, we, i2h1, i2h2, h2o, bias, hinit,
                                        hcat_u, h2oT_u);
    k_pass_a<<<dim3(NVT, 4), 256, 0, stream>>>(
        (const __bf16*)hcat_u, (const __bf16*)h2oT_u, Asum2);
    k_pass_b<<<dim3(NVT, NMT), 256, 0, stream>>>(
        (const __bf16*)hcat_u, (const __bf16*)h2oT_u, Asum2, out);
}

// Round 11
// 244.180 us; speedup vs baseline: 1.5653x; 1.5653x over previous
//
#include <hip/hip_runtime.h>

// Problem constants
#define V_SZ 32000
#define E_SZ 128
#define H_SZ 32
#define L_SZ 64
#define B_SZ 32
#define M_TOT 2048   // L*B rows
#define K2 64        // 2H
#define NVT 125      // V/256 col-slices
#define NMT 32       // M_TOT/64 row-tiles
#define NPART 250    // sum-exp partials per row (125 xcol x 2 wn)

typedef __bf16 bf16x8 __attribute__((ext_vector_type(8)));
typedef float f32x4 __attribute__((ext_vector_type(4)));

__device__ __forceinline__ unsigned short f2bf(float f) {
    unsigned int u = __float_as_uint(f);
    u += 0x7FFFu + ((u >> 16) & 1u);   // round-to-nearest-even
    return (unsigned short)(u >> 16);
}

// ---------------------------------------------------------------------------
// Proven helpers (R6/R8): B fragments resident before MFMA; 64x256 tile GEMM.
// C layout: row = wm*32 + m*16 + lg*4 + r, col = wn*128 + n*16 + lr.
// ---------------------------------------------------------------------------
__device__ __forceinline__ void load_bfrag(
    const __bf16* __restrict__ h2oT, int xcol, int wn, int lg, int lr,
    bf16x8 bfr[8][2]) {
    const int colbase = xcol * 256;
#pragma unroll
    for (int n = 0; n < 8; ++n) {
        int col = colbase + wn * 128 + n * 16 + lr;
        const __bf16* bp = h2oT + (size_t)col * K2 + lg * 8;
        bfr[n][0] = *(const bf16x8*)(bp);
        bfr[n][1] = *(const bf16x8*)(bp + 32);
    }
}

__device__ __forceinline__ void tile_gemm(
    const __bf16* __restrict__ hcat, int rowbase, int wm, int lg, int lr,
    const bf16x8 bfr[8][2], f32x4 acc[2][8]) {
    bf16x8 af[2][2];
#pragma unroll
    for (int m = 0; m < 2; ++m) {
        int row = rowbase + wm * 32 + m * 16 + lr;
#pragma unroll
        for (int kh = 0; kh < 2; ++kh)
            af[m][kh] = *(const bf16x8*)(hcat + row * K2 + kh * 32 + lg * 8);
    }
#pragma unroll
    for (int m = 0; m < 2; ++m)
#pragma unroll
        for (int n = 0; n < 8; ++n) acc[m][n] = (f32x4){0.f, 0.f, 0.f, 0.f};
#pragma unroll
    for (int n = 0; n < 8; ++n)
#pragma unroll
        for (int m = 0; m < 2; ++m) {
            acc[m][n] = __builtin_amdgcn_mfma_f32_16x16x32_bf16(af[m][0], bfr[n][0], acc[m][n], 0, 0, 0);
            acc[m][n] = __builtin_amdgcn_mfma_f32_16x16x32_bf16(af[m][1], bfr[n][1], acc[m][n], 0, 0, 0);
        }
}

// ---------------------------------------------------------------------------
// Kernel 1: blocks 0..124  -> transpose+convert h2o -> h2oT (256 rows each)
//           blocks 125..156 -> emb-GEMM into LDS + RNN recurrence
// (unchanged, proven since R6)
// ---------------------------------------------------------------------------
__global__ __launch_bounds__(256) void k_prep_rnn(
    const int* __restrict__ inp, const float* __restrict__ we,
    const float* __restrict__ i2h1, const float* __restrict__ i2h2,
    const float* __restrict__ h2o, const float* __restrict__ bias,
    const float* __restrict__ hinit,
    unsigned short* __restrict__ hcat_u, unsigned short* __restrict__ h2oT_u) {
    const int tid = threadIdx.x;
    const int p = blockIdx.x;
    if (p < 125) {
        const int v = p * 256 + tid;               // [0,32000) exact
        unsigned int* dst = (unsigned int*)(h2oT_u + (size_t)v * K2);
#pragma unroll
        for (int k = 0; k < K2; k += 2) {
            float a = h2o[(size_t)k * V_SZ + v];
            float b = h2o[(size_t)(k + 1) * V_SZ + v];
            dst[k >> 1] = (unsigned int)f2bf(a) | ((unsigned int)f2bf(b) << 16);
        }
        return;
    }
    // ---- emb + RNN block (one direction, 2 batch rows) ----
    const int w2 = p - 125;                        // 0..31
    const int dir = w2 >> 4;
    const int bpair = w2 & 15;
    const float* W = dir ? i2h2 : i2h1;
    __shared__ float Xl[L_SZ * 2 * H_SZ];          // 16 KB: X[t][bb][j]
    {
        const int j = tid & 31, bb = (tid >> 5) & 1, to = tid >> 6;
        const int b = bpair * 2 + bb;
        const float bj = bias[j];
        for (int tt = 0; tt < 16; ++tt) {
            const int t = to * 16 + tt;
            const int idx = inp[t * B_SZ + b];
            const float* er = we + (size_t)idx * E_SZ;
            float acc = bj;
#pragma unroll
            for (int k0 = 0; k0 < E_SZ; k0 += 4) {
                f32x4 e4 = *(const f32x4*)(er + k0);
                acc += e4.x * W[(k0 + 0) * H_SZ + j];
                acc += e4.y * W[(k0 + 1) * H_SZ + j];
                acc += e4.z * W[(k0 + 2) * H_SZ + j];
                acc += e4.w * W[(k0 + 3) * H_SZ + j];
            }
            Xl[(t * 2 + bb) * H_SZ + j] = acc;
        }
    }
    __syncthreads();
    if (tid < 64) {
        const int lane = tid;
        const int bb = lane >> 5;
        const int b = bpair * 2 + bb;
        const int j = lane & 31;
        const int srcbase = lane & 32;
        float wh[H_SZ];
#pragma unroll
        for (int k = 0; k < H_SZ; ++k) wh[k] = W[(E_SZ + k) * H_SZ + j];
        float h = hinit[j];
        for (int step = 0; step < L_SZ; ++step) {
            const int tt = dir ? (L_SZ - 1 - step) : step;
            hcat_u[(tt * B_SZ + b) * K2 + dir * H_SZ + j] = f2bf(h);
            float a0 = Xl[(tt * 2 + bb) * H_SZ + j];
            float a1 = 0.f, a2 = 0.f, a3 = 0.f;
#pragma unroll
            for (int k = 0; k < H_SZ; k += 4) {
                a0 += __shfl(h, srcbase | k, 64) * wh[k];
                a1 += __shfl(h, srcbase | (k + 1), 64) * wh[k + 1];
                a2 += __shfl(h, srcbase | (k + 2), 64) * wh[k + 2];
                a3 += __shfl(h, srcbase | (k + 3), 64) * wh[k + 3];
            }
            float x2 = (a0 + a1) + (a2 + a3);
            float e = __expf(2.f * x2);            // tanh = 1 - 2/(e^{2x}+1)
            h = 1.f - 2.f * __builtin_amdgcn_rcpf(e + 1.f);
        }
    }
}

// ---------------------------------------------------------------------------
// Kernel 2 (pass A): grid (125,16), 2 tiles/block, BARRIER-FREE, zero LDS.
// Per-wave sum-exp partials written TRANSPOSED: Asum[pcol][row], coalesced
// consumption in pass B. Tile 1's loads/MFMAs overlap tile 0's exp drain.
// ---------------------------------------------------------------------------
__global__ __launch_bounds__(256) void k_pass_a(
    const __bf16* __restrict__ hcat, const __bf16* __restrict__ h2oT,
    float* __restrict__ Asum) {
    const int tid = threadIdx.x;
    const int wave = tid >> 6, lane = tid & 63;
    const int wm = wave >> 1, wn = wave & 1;
    const int lg = lane >> 4, lr = lane & 15;
    const int xcol = blockIdx.x;
    const int pcol = xcol * 2 + wn;

    bf16x8 bfr[8][2];
    load_bfrag(h2oT, xcol, wn, lg, lr, bfr);

#pragma unroll
    for (int jt = 0; jt < 2; ++jt) {
        const int rowbase = (blockIdx.y * 2 + jt) * 64;
        f32x4 acc[2][8];
        tile_gemm(hcat, rowbase, wm, lg, lr, bfr, acc);
        float rs[2][4];
#pragma unroll
        for (int m = 0; m < 2; ++m)
#pragma unroll
            for (int r = 0; r < 4; ++r) {
                float s = 0.f;
#pragma unroll
                for (int n = 0; n < 8; ++n) s += __expf(acc[m][n][r]);
                rs[m][r] = s;
            }
#pragma unroll
        for (int mask = 1; mask < 16; mask <<= 1)
#pragma unroll
            for (int m = 0; m < 2; ++m)
#pragma unroll
                for (int r = 0; r < 4; ++r)
                    rs[m][r] += __shfl_xor(rs[m][r], mask, 64);
        if (lr == 0) {
#pragma unroll
            for (int m = 0; m < 2; ++m)
#pragma unroll
                for (int r = 0; r < 4; ++r) {
                    const int row = rowbase + wm * 32 + m * 16 + lg * 4 + r;
                    Asum[(size_t)pcol * M_TOT + row] = rs[m][r];
                }
        }
    }
}

// ---------------------------------------------------------------------------
// Kernel 3 (pass B + coalesced fused lse): per block,
//  (1) issue B/A fragment loads (hide ramp under lse phase),
//  (2) lse: wave q sums partials p in [q*63, ...) for all 64 rows, lane=row
//      -> fully coalesced 256B reads of Asum[p][rowbase+lane] (L2-resident),
//  (3) MFMA recompute, (4) two-chunk LDS repack -> coalesced f32x4 stores.
// grid (125,32).
// ---------------------------------------------------------------------------
__global__ __launch_bounds__(256) void k_pass_b(
    const __bf16* __restrict__ hcat, const __bf16* __restrict__ h2oT,
    const float* __restrict__ Asum, float* __restrict__ out) {
    const int tid = threadIdx.x;
    const int wave = tid >> 6, lane = tid & 63;
    const int wm = wave >> 1, wn = wave & 1;
    const int lg = lane >> 4, lr = lane & 15;
    const int rowbase = blockIdx.y * 64;
    const int colbase = blockIdx.x * 256;

    __shared__ float cbuf[32 * 260];   // 33.3 KB; pad 260 breaks conflicts
    float (*part)[64] = (float(*)[64])cbuf;        // aliased; freed by barrier
    __shared__ float lse_s[64];

    // ---- (1) issue fragment loads ----
    bf16x8 bfr[8][2];
    load_bfrag(h2oT, blockIdx.x, wn, lg, lr, bfr);
    bf16x8 af[2][2];
#pragma unroll
    for (int m = 0; m < 2; ++m) {
        int row = rowbase + wm * 32 + m * 16 + lr;
#pragma unroll
        for (int kh = 0; kh < 2; ++kh)
            af[m][kh] = *(const bf16x8*)(hcat + row * K2 + kh * 32 + lg * 8);
    }

    // ---- (2) lse for the 64 rows (coalesced: lane = row) ----
    {
        const int i0 = wave * 63;
        const int i1 = (wave == 3) ? NPART : (i0 + 63);
        float s = 0.f;
        for (int i = i0; i < i1; ++i)
            s += Asum[(size_t)i * M_TOT + rowbase + lane];
        part[wave][lane] = s;
    }
    __syncthreads();
    if (tid < 64)
        lse_s[tid] = logf(part[0][tid] + part[1][tid] + part[2][tid] + part[3][tid]);
    __syncthreads();                   // lse_s ready; part (cbuf) now free

    // ---- (3) MFMA recompute ----
    f32x4 acc[2][8];
#pragma unroll
    for (int m = 0; m < 2; ++m)
#pragma unroll
        for (int n = 0; n < 8; ++n) acc[m][n] = (f32x4){0.f, 0.f, 0.f, 0.f};
#pragma unroll
    for (int n = 0; n < 8; ++n)
#pragma unroll
        for (int m = 0; m < 2; ++m) {
            acc[m][n] = __builtin_amdgcn_mfma_f32_16x16x32_bf16(af[m][0], bfr[n][0], acc[m][n], 0, 0, 0);
            acc[m][n] = __builtin_amdgcn_mfma_f32_16x16x32_bf16(af[m][1], bfr[n][1], acc[m][n], 0, 0, 0);
        }
    float lsev[2][4];
#pragma unroll
    for (int m = 0; m < 2; ++m)
#pragma unroll
        for (int r = 0; r < 4; ++r)
            lsev[m][r] = lse_s[wm * 32 + m * 16 + lg * 4 + r];

    // ---- (4) two-chunk LDS repack -> coalesced f32x4 stores ----
#pragma unroll
    for (int c = 0; c < 2; ++c) {
        if (c) __syncthreads();        // WAR guard on cbuf reuse
#pragma unroll
        for (int n = 0; n < 8; ++n)
#pragma unroll
            for (int r = 0; r < 4; ++r)
                cbuf[(wm * 16 + lg * 4 + r) * 260 + wn * 128 + n * 16 + lr] =
                    acc[c][n][r] - lsev[c][r];
        __syncthreads();
#pragma unroll
        for (int it = 0; it < 8; ++it) {
            int idx4 = it * 256 + tid;     // float4 index in 32x256 chunk
            int lrow = idx4 >> 6;          // 64 float4 per row
            int col = (idx4 & 63) << 2;
            int grow = rowbase + (lrow >> 4) * 32 + c * 16 + (lrow & 15);
            f32x4 v = *(const f32x4*)&cbuf[lrow * 260 + col];
            *(f32x4*)(out + (size_t)grow * V_SZ + colbase + col) = v;
        }
    }
}

// ---------------------------------------------------------------------------
extern "C" void kernel_launch(void* const* d_in, const int* in_sizes, int n_in,
                              void* d_out, int out_size, void* d_ws, size_t ws_size,
                              hipStream_t stream) {
    (void)in_sizes; (void)n_in; (void)out_size; (void)ws_size;
    const int*   inp   = (const int*)d_in[0];
    const float* we    = (const float*)d_in[1];
    const float* i2h1  = (const float*)d_in[2];
    const float* i2h2  = (const float*)d_in[3];
    const float* h2o   = (const float*)d_in[4];
    const float* bias  = (const float*)d_in[5];
    const float* hinit = (const float*)d_in[6];
    float* out = (float*)d_out;
    char* ws = (char*)d_ws;
    unsigned short* hcat_u = (unsigned short*)(ws);           //  262144 B
    unsigned short* h2oT_u = (unsigned short*)(ws + 262144);  // 4096000 B
    float*          Asum   = (float*)(ws + 4358144);          // 2048000 B

    k_prep_rnn<<<157, 256, 0, stream>>>(inp, we, i2h1, i2h2, h2o, bias, hinit,
                                        hcat_u, h2oT_u);
    k_pass_a<<<dim3(NVT, 16), 256, 0, stream>>>(
        (const __bf16*)hcat_u, (const __bf16*)h2oT_u, Asum);
    k_pass_b<<<dim3(NVT, NMT), 256, 0, stream>>>(
        (const __bf16*)hcat_u, (const __bf16*)h2oT_u, Asum, out);
}

// Round 12
// 190.210 us; speedup vs baseline: 2.0094x; 1.2837x over previous
//
#include <hip/hip_runtime.h>

// Problem constants
#define V_SZ 32000
#define E_SZ 128
#define H_SZ 32
#define L_SZ 64
#define B_SZ 32
#define M_TOT 2048   // L*B rows
#define K2 64        // 2H
#define NVT 125      // V/256 col-slices
#define NMT 32       // M_TOT/64 row-tiles
#define NPART 500    // sum-exp partials per row (125 xcol x 4 waves)

typedef __bf16 bf16x8 __attribute__((ext_vector_type(8)));
typedef float f32x4 __attribute__((ext_vector_type(4)));

__device__ __forceinline__ unsigned short f2bf(float f) {
    unsigned int u = __float_as_uint(f);
    u += 0x7FFFu + ((u >> 16) & 1u);   // round-to-nearest-even
    return (unsigned short)(u >> 16);
}

// ---------------------------------------------------------------------------
// Swapped-operand fragment loads. Both MFMA operands use lane layout
// {index = lane&15, k = (lane>>4)*8 .. +8}, so vocab-as-M / hcatrow-as-N is
// just an argument swap. D: vocab = (lane>>4)*4 + reg, hrow = lane&15
// -> each lane's reg quad is 4 CONSECUTIVE vocab of one output row.
// Per wave: 64 vocab x 64 rows; block (4 waves) = 256 vocab x 64 rows.
// ---------------------------------------------------------------------------
__device__ __forceinline__ void load_vfrag(
    const __bf16* __restrict__ h2oT, int vbase, int lg, int lr,
    bf16x8 vf[4][2]) {
#pragma unroll
    for (int i = 0; i < 4; ++i) {
        const __bf16* vp = h2oT + (size_t)(vbase + i * 16 + lr) * K2 + lg * 8;
        vf[i][0] = *(const bf16x8*)(vp);
        vf[i][1] = *(const bf16x8*)(vp + 32);
    }
}

__device__ __forceinline__ void load_hfrag(
    const __bf16* __restrict__ hcat, int rowbase, int lg, int lr,
    bf16x8 hf[4][2]) {
#pragma unroll
    for (int j = 0; j < 4; ++j) {
        const __bf16* hp = hcat + (size_t)(rowbase + j * 16 + lr) * K2 + lg * 8;
        hf[j][0] = *(const bf16x8*)(hp);
        hf[j][1] = *(const bf16x8*)(hp + 32);
    }
}

__device__ __forceinline__ void tile_gemm_t(
    const bf16x8 vf[4][2], const bf16x8 hf[4][2], f32x4 acc[4][4]) {
#pragma unroll
    for (int i = 0; i < 4; ++i)
#pragma unroll
        for (int j = 0; j < 4; ++j) acc[i][j] = (f32x4){0.f, 0.f, 0.f, 0.f};
#pragma unroll
    for (int i = 0; i < 4; ++i)
#pragma unroll
        for (int j = 0; j < 4; ++j) {
            acc[i][j] = __builtin_amdgcn_mfma_f32_16x16x32_bf16(vf[i][0], hf[j][0], acc[i][j], 0, 0, 0);
            acc[i][j] = __builtin_amdgcn_mfma_f32_16x16x32_bf16(vf[i][1], hf[j][1], acc[i][j], 0, 0, 0);
        }
}

// ---------------------------------------------------------------------------
// Kernel 1: blocks 0..124  -> transpose+convert h2o -> h2oT (256 rows each)
//           blocks 125..156 -> emb-GEMM into LDS + RNN recurrence
// (unchanged, proven since R6)
// ---------------------------------------------------------------------------
__global__ __launch_bounds__(256) void k_prep_rnn(
    const int* __restrict__ inp, const float* __restrict__ we,
    const float* __restrict__ i2h1, const float* __restrict__ i2h2,
    const float* __restrict__ h2o, const float* __restrict__ bias,
    const float* __restrict__ hinit,
    unsigned short* __restrict__ hcat_u, unsigned short* __restrict__ h2oT_u) {
    const int tid = threadIdx.x;
    const int p = blockIdx.x;
    if (p < 125) {
        const int v = p * 256 + tid;               // [0,32000) exact
        unsigned int* dst = (unsigned int*)(h2oT_u + (size_t)v * K2);
#pragma unroll
        for (int k = 0; k < K2; k += 2) {
            float a = h2o[(size_t)k * V_SZ + v];
            float b = h2o[(size_t)(k + 1) * V_SZ + v];
            dst[k >> 1] = (unsigned int)f2bf(a) | ((unsigned int)f2bf(b) << 16);
        }
        return;
    }
    // ---- emb + RNN block (one direction, 2 batch rows) ----
    const int w2 = p - 125;                        // 0..31
    const int dir = w2 >> 4;
    const int bpair = w2 & 15;
    const float* W = dir ? i2h2 : i2h1;
    __shared__ float Xl[L_SZ * 2 * H_SZ];          // 16 KB: X[t][bb][j]
    {
        const int j = tid & 31, bb = (tid >> 5) & 1, to = tid >> 6;
        const int b = bpair * 2 + bb;
        const float bj = bias[j];
        for (int tt = 0; tt < 16; ++tt) {
            const int t = to * 16 + tt;
            const int idx = inp[t * B_SZ + b];
            const float* er = we + (size_t)idx * E_SZ;
            float acc = bj;
#pragma unroll
            for (int k0 = 0; k0 < E_SZ; k0 += 4) {
                f32x4 e4 = *(const f32x4*)(er + k0);
                acc += e4.x * W[(k0 + 0) * H_SZ + j];
                acc += e4.y * W[(k0 + 1) * H_SZ + j];
                acc += e4.z * W[(k0 + 2) * H_SZ + j];
                acc += e4.w * W[(k0 + 3) * H_SZ + j];
            }
            Xl[(t * 2 + bb) * H_SZ + j] = acc;
        }
    }
    __syncthreads();
    if (tid < 64) {
        const int lane = tid;
        const int bb = lane >> 5;
        const int b = bpair * 2 + bb;
        const int j = lane & 31;
        const int srcbase = lane & 32;
        float wh[H_SZ];
#pragma unroll
        for (int k = 0; k < H_SZ; ++k) wh[k] = W[(E_SZ + k) * H_SZ + j];
        float h = hinit[j];
        for (int step = 0; step < L_SZ; ++step) {
            const int tt = dir ? (L_SZ - 1 - step) : step;
            hcat_u[(tt * B_SZ + b) * K2 + dir * H_SZ + j] = f2bf(h);
            float a0 = Xl[(tt * 2 + bb) * H_SZ + j];
            float a1 = 0.f, a2 = 0.f, a3 = 0.f;
#pragma unroll
            for (int k = 0; k < H_SZ; k += 4) {
                a0 += __shfl(h, srcbase | k, 64) * wh[k];
                a1 += __shfl(h, srcbase | (k + 1), 64) * wh[k + 1];
                a2 += __shfl(h, srcbase | (k + 2), 64) * wh[k + 2];
                a3 += __shfl(h, srcbase | (k + 3), 64) * wh[k + 3];
            }
            float x2 = (a0 + a1) + (a2 + a3);
            float e = __expf(2.f * x2);            // tanh = 1 - 2/(e^{2x}+1)
            h = 1.f - 2.f * __builtin_amdgcn_rcpf(e + 1.f);
        }
    }
}

// ---------------------------------------------------------------------------
// Kernel 2 (pass A): grid (125,32), ZERO LDS, ZERO barriers. Swapped-operand
// GEMM; vocab reduce = 4 regs (local) + shfl 16/32 (2 rounds). Partials
// written transposed Asum[pcol][row], pcol = xcol*4 + wave.
// ---------------------------------------------------------------------------
__global__ __launch_bounds__(256) void k_pass_a(
    const __bf16* __restrict__ hcat, const __bf16* __restrict__ h2oT,
    float* __restrict__ Asum) {
    const int tid = threadIdx.x;
    const int wave = tid >> 6, lane = tid & 63;
    const int lg = lane >> 4, lr = lane & 15;
    const int rowbase = blockIdx.y * 64;
    const int vbase = blockIdx.x * 256 + wave * 64;

    bf16x8 vf[4][2], hf[4][2];
    load_vfrag(h2oT, vbase, lg, lr, vf);
    load_hfrag(hcat, rowbase, lg, lr, hf);
    f32x4 acc[4][4];
    tile_gemm_t(vf, hf, acc);

    float srow[4];
#pragma unroll
    for (int j = 0; j < 4; ++j) {
        float s = 0.f;
#pragma unroll
        for (int i = 0; i < 4; ++i)
#pragma unroll
            for (int r = 0; r < 4; ++r) s += __expf(acc[i][j][r]);
        srow[j] = s;
    }
#pragma unroll
    for (int j = 0; j < 4; ++j) {
        srow[j] += __shfl_xor(srow[j], 16, 64);
        srow[j] += __shfl_xor(srow[j], 32, 64);
    }
    if (lane < 16) {
        const int pcol = blockIdx.x * 4 + wave;
#pragma unroll
        for (int j = 0; j < 4; ++j)
            Asum[(size_t)pcol * M_TOT + rowbase + j * 16 + lane] = srow[j];
    }
}

// ---------------------------------------------------------------------------
// Kernel 3: reduce 500 partials -> lse[row] = log(sum). Coalesced (lane=row).
// ---------------------------------------------------------------------------
__global__ __launch_bounds__(256) void k_lse(
    const float* __restrict__ Asum, float* __restrict__ lse) {
    const int row = blockIdx.x * 256 + threadIdx.x;
    float s = 0.f;
    for (int i = 0; i < NPART; ++i) s += Asum[(size_t)i * M_TOT + row];
    lse[row] = logf(s);
}

// ---------------------------------------------------------------------------
// Kernel 4 (pass B): ZERO LDS, ZERO barriers. Swapped-operand GEMM; each
// lane's reg quad = 4 consecutive vocab of one row -> direct f32x4 stores
// (lanes {l,l+16,l+32,l+48} form 64B row segments). grid (125,32).
// ---------------------------------------------------------------------------
__global__ __launch_bounds__(256) void k_pass_b(
    const __bf16* __restrict__ hcat, const __bf16* __restrict__ h2oT,
    const float* __restrict__ lse, float* __restrict__ out) {
    const int tid = threadIdx.x;
    const int wave = tid >> 6, lane = tid & 63;
    const int lg = lane >> 4, lr = lane & 15;
    const int rowbase = blockIdx.y * 64;
    const int vbase = blockIdx.x * 256 + wave * 64;

    bf16x8 vf[4][2], hf[4][2];
    load_vfrag(h2oT, vbase, lg, lr, vf);
    load_hfrag(hcat, rowbase, lg, lr, hf);
    float lsev[4];
#pragma unroll
    for (int j = 0; j < 4; ++j)
        lsev[j] = lse[rowbase + j * 16 + lr];

    f32x4 acc[4][4];
    tile_gemm_t(vf, hf, acc);

#pragma unroll
    for (int j = 0; j < 4; ++j) {
        float* rp = out + (size_t)(rowbase + j * 16 + lr) * V_SZ + vbase + lg * 4;
#pragma unroll
        for (int i = 0; i < 4; ++i) {
            f32x4 v;
            v.x = acc[i][j].x - lsev[j];
            v.y = acc[i][j].y - lsev[j];
            v.z = acc[i][j].z - lsev[j];
            v.w = acc[i][j].w - lsev[j];
            *(f32x4*)(rp + i * 16) = v;
        }
    }
}

// ---------------------------------------------------------------------------
extern "C" void kernel_launch(void* const* d_in, const int* in_sizes, int n_in,
                              void* d_out, int out_size, void* d_ws, size_t ws_size,
                              hipStream_t stream) {
    (void)in_sizes; (void)n_in; (void)out_size; (void)ws_size;
    const int*   inp   = (const int*)d_in[0];
    const float* we    = (const float*)d_in[1];
    const float* i2h1  = (const float*)d_in[2];
    const float* i2h2  = (const float*)d_in[3];
    const float* h2o   = (const float*)d_in[4];
    const float* bias  = (const float*)d_in[5];
    const float* hinit = (const float*)d_in[6];
    float* out = (float*)d_out;
    char* ws = (char*)d_ws;
    unsigned short* hcat_u = (unsigned short*)(ws);           //  262144 B
    unsigned short* h2oT_u = (unsigned short*)(ws + 262144);  // 4096000 B
    float*          Asum   = (float*)(ws + 4358144);          // 4096000 B
    float*          lse    = (float*)(ws + 8454144);          //    8192 B

    k_prep_rnn<<<157, 256, 0, stream>>>(inp, we, i2h1, i2h2, h2o, bias, hinit,
                                        hcat_u, h2oT_u);
    k_pass_a<<<dim3(NVT, NMT), 256, 0, stream>>>(
        (const __bf16*)hcat_u, (const __bf16*)h2oT_u, Asum);
    k_lse<<<8, 256, 0, stream>>>(Asum, lse);
    k_pass_b<<<dim3(NVT, NMT), 256, 0, stream>>>(
        (const __bf16*)hcat_u, (const __bf16*)h2oT_u, lse, out);
}

// Round 13
// 159.827 us; speedup vs baseline: 2.3914x; 1.1901x over previous
//
#include <hip/hip_runtime.h>

// Problem constants
#define V_SZ 32000
#define E_SZ 128
#define H_SZ 32
#define L_SZ 64
#define B_SZ 32
#define M_TOT 2048   // L*B rows
#define K2 64        // 2H
#define NVT 125      // V/256 col-slices
#define NPART 500    // sum-exp partials per row (125 xcol x 4 waves)

typedef __bf16 bf16x8 __attribute__((ext_vector_type(8)));
typedef float f32x4 __attribute__((ext_vector_type(4)));

__device__ __forceinline__ unsigned short f2bf(float f) {
    unsigned int u = __float_as_uint(f);
    u += 0x7FFFu + ((u >> 16) & 1u);   // round-to-nearest-even
    return (unsigned short)(u >> 16);
}

// ---------------------------------------------------------------------------
// Swapped-operand fragments (R12-proven): vocab-as-M, hcat-rows-as-N.
// D: vocab = vbase + i*16 + lg*4 + reg, hrow = rowbase + j*16 + lr
// -> each lane's reg quad = 4 consecutive vocab of one output row.
// ---------------------------------------------------------------------------
__device__ __forceinline__ void load_vfrag(
    const __bf16* __restrict__ h2oT, int vbase, int lg, int lr,
    bf16x8 vf[4][2]) {
#pragma unroll
    for (int i = 0; i < 4; ++i) {
        const __bf16* vp = h2oT + (size_t)(vbase + i * 16 + lr) * K2 + lg * 8;
        vf[i][0] = *(const bf16x8*)(vp);
        vf[i][1] = *(const bf16x8*)(vp + 32);
    }
}

__device__ __forceinline__ void load_hfrag(
    const __bf16* __restrict__ hcat, int rowbase, int lg, int lr,
    bf16x8 hf[4][2]) {
#pragma unroll
    for (int j = 0; j < 4; ++j) {
        const __bf16* hp = hcat + (size_t)(rowbase + j * 16 + lr) * K2 + lg * 8;
        hf[j][0] = *(const bf16x8*)(hp);
        hf[j][1] = *(const bf16x8*)(hp + 32);
    }
}

__device__ __forceinline__ void tile_gemm_t(
    const bf16x8 vf[4][2], const bf16x8 hf[4][2], f32x4 acc[4][4]) {
#pragma unroll
    for (int i = 0; i < 4; ++i)
#pragma unroll
        for (int j = 0; j < 4; ++j) acc[i][j] = (f32x4){0.f, 0.f, 0.f, 0.f};
#pragma unroll
    for (int i = 0; i < 4; ++i)
#pragma unroll
        for (int j = 0; j < 4; ++j) {
            acc[i][j] = __builtin_amdgcn_mfma_f32_16x16x32_bf16(vf[i][0], hf[j][0], acc[i][j], 0, 0, 0);
            acc[i][j] = __builtin_amdgcn_mfma_f32_16x16x32_bf16(vf[i][1], hf[j][1], acc[i][j], 0, 0, 0);
        }
}

// ---------------------------------------------------------------------------
// Kernel 1: blocks 0..124  -> transpose+convert h2o -> h2oT (256 rows each)
//           blocks 125..156 -> emb-GEMM into LDS + RNN recurrence
// (unchanged, proven since R6)
// ---------------------------------------------------------------------------
__global__ __launch_bounds__(256) void k_prep_rnn(
    const int* __restrict__ inp, const float* __restrict__ we,
    const float* __restrict__ i2h1, const float* __restrict__ i2h2,
    const float* __restrict__ h2o, const float* __restrict__ bias,
    const float* __restrict__ hinit,
    unsigned short* __restrict__ hcat_u, unsigned short* __restrict__ h2oT_u) {
    const int tid = threadIdx.x;
    const int p = blockIdx.x;
    if (p < 125) {
        const int v = p * 256 + tid;               // [0,32000) exact
        unsigned int* dst = (unsigned int*)(h2oT_u + (size_t)v * K2);
#pragma unroll
        for (int k = 0; k < K2; k += 2) {
            float a = h2o[(size_t)k * V_SZ + v];
            float b = h2o[(size_t)(k + 1) * V_SZ + v];
            dst[k >> 1] = (unsigned int)f2bf(a) | ((unsigned int)f2bf(b) << 16);
        }
        return;
    }
    // ---- emb + RNN block (one direction, 2 batch rows) ----
    const int w2 = p - 125;                        // 0..31
    const int dir = w2 >> 4;
    const int bpair = w2 & 15;
    const float* W = dir ? i2h2 : i2h1;
    __shared__ float Xl[L_SZ * 2 * H_SZ];          // 16 KB: X[t][bb][j]
    {
        const int j = tid & 31, bb = (tid >> 5) & 1, to = tid >> 6;
        const int b = bpair * 2 + bb;
        const float bj = bias[j];
        for (int tt = 0; tt < 16; ++tt) {
            const int t = to * 16 + tt;
            const int idx = inp[t * B_SZ + b];
            const float* er = we + (size_t)idx * E_SZ;
            float acc = bj;
#pragma unroll
            for (int k0 = 0; k0 < E_SZ; k0 += 4) {
                f32x4 e4 = *(const f32x4*)(er + k0);
                acc += e4.x * W[(k0 + 0) * H_SZ + j];
                acc += e4.y * W[(k0 + 1) * H_SZ + j];
                acc += e4.z * W[(k0 + 2) * H_SZ + j];
                acc += e4.w * W[(k0 + 3) * H_SZ + j];
            }
            Xl[(t * 2 + bb) * H_SZ + j] = acc;
        }
    }
    __syncthreads();
    if (tid < 64) {
        const int lane = tid;
        const int bb = lane >> 5;
        const int b = bpair * 2 + bb;
        const int j = lane & 31;
        const int srcbase = lane & 32;
        float wh[H_SZ];
#pragma unroll
        for (int k = 0; k < H_SZ; ++k) wh[k] = W[(E_SZ + k) * H_SZ + j];
        float h = hinit[j];
        for (int step = 0; step < L_SZ; ++step) {
            const int tt = dir ? (L_SZ - 1 - step) : step;
            hcat_u[(tt * B_SZ + b) * K2 + dir * H_SZ + j] = f2bf(h);
            float a0 = Xl[(tt * 2 + bb) * H_SZ + j];
            float a1 = 0.f, a2 = 0.f, a3 = 0.f;
#pragma unroll
            for (int k = 0; k < H_SZ; k += 4) {
                a0 += __shfl(h, srcbase | k, 64) * wh[k];
                a1 += __shfl(h, srcbase | (k + 1), 64) * wh[k + 1];
                a2 += __shfl(h, srcbase | (k + 2), 64) * wh[k + 2];
                a3 += __shfl(h, srcbase | (k + 3), 64) * wh[k + 3];
            }
            float x2 = (a0 + a1) + (a2 + a3);
            float e = __expf(2.f * x2);            // tanh = 1 - 2/(e^{2x}+1)
            h = 1.f - 2.f * __builtin_amdgcn_rcpf(e + 1.f);
        }
    }
}

// ---------------------------------------------------------------------------
// Kernel 2 (pass A): grid (125,8), 4 row-tiles/block, zero LDS/barriers.
// vfrag loaded once; hfrag double-buffered so tile t+1's loads overlap
// tile t's MFMA + exp/shfl epilogue. Partials -> Asum[pcol][row].
// ---------------------------------------------------------------------------
__global__ __launch_bounds__(256) void k_pass_a(
    const __bf16* __restrict__ hcat, const __bf16* __restrict__ h2oT,
    float* __restrict__ Asum) {
    const int tid = threadIdx.x;
    const int wave = tid >> 6, lane = tid & 63;
    const int lg = lane >> 4, lr = lane & 15;
    const int y0 = blockIdx.y * 256;               // 4 tiles x 64 rows
    const int vbase = blockIdx.x * 256 + wave * 64;
    const int pcol = blockIdx.x * 4 + wave;

    bf16x8 vf[4][2];
    load_vfrag(h2oT, vbase, lg, lr, vf);

    auto epilogue = [&](const bf16x8 hf[4][2], int rowbase) {
        f32x4 acc[4][4];
        tile_gemm_t(vf, hf, acc);
        float srow[4];
#pragma unroll
        for (int j = 0; j < 4; ++j) {
            float s = 0.f;
#pragma unroll
            for (int i = 0; i < 4; ++i)
#pragma unroll
                for (int r = 0; r < 4; ++r) s += __expf(acc[i][j][r]);
            srow[j] = s;
        }
#pragma unroll
        for (int j = 0; j < 4; ++j) {
            srow[j] += __shfl_xor(srow[j], 16, 64);
            srow[j] += __shfl_xor(srow[j], 32, 64);
        }
        if (lane < 16) {
#pragma unroll
            for (int j = 0; j < 4; ++j)
                Asum[(size_t)pcol * M_TOT + rowbase + j * 16 + lane] = srow[j];
        }
    };

    bf16x8 hfA[4][2], hfB[4][2];
    load_hfrag(hcat, y0, lg, lr, hfA);
    load_hfrag(hcat, y0 + 64, lg, lr, hfB);        // in flight during tile 0
    epilogue(hfA, y0);
    load_hfrag(hcat, y0 + 128, lg, lr, hfA);       // in flight during tile 1
    epilogue(hfB, y0 + 64);
    load_hfrag(hcat, y0 + 192, lg, lr, hfB);       // in flight during tile 2
    epilogue(hfA, y0 + 128);
    epilogue(hfB, y0 + 192);
}

// ---------------------------------------------------------------------------
// Kernel 3: reduce 500 partials -> lse[row] = log(sum). Coalesced (lane=row).
// ---------------------------------------------------------------------------
__global__ __launch_bounds__(256) void k_lse(
    const float* __restrict__ Asum, float* __restrict__ lse) {
    const int row = blockIdx.x * 256 + threadIdx.x;
    float s = 0.f;
    for (int i = 0; i < NPART; ++i) s += Asum[(size_t)i * M_TOT + row];
    lse[row] = logf(s);
}

// ---------------------------------------------------------------------------
// Kernel 4 (pass B): grid (125,8), 4 row-tiles/block, zero LDS/barriers.
// vfrag loaded once; hfrag double-buffered; direct f32x4 stores from regs
// (lanes {l,l+16,l+32,l+48} form 64B row segments; 256B/row/wave total).
// ---------------------------------------------------------------------------
__global__ __launch_bounds__(256) void k_pass_b(
    const __bf16* __restrict__ hcat, const __bf16* __restrict__ h2oT,
    const float* __restrict__ lse, float* __restrict__ out) {
    const int tid = threadIdx.x;
    const int wave = tid >> 6, lane = tid & 63;
    const int lg = lane >> 4, lr = lane & 15;
    const int y0 = blockIdx.y * 256;               // 4 tiles x 64 rows
    const int vbase = blockIdx.x * 256 + wave * 64;

    bf16x8 vf[4][2];
    load_vfrag(h2oT, vbase, lg, lr, vf);

    auto epilogue = [&](const bf16x8 hf[4][2], int rowbase) {
        float lsev[4];
#pragma unroll
        for (int j = 0; j < 4; ++j)
            lsev[j] = lse[rowbase + j * 16 + lr];
        f32x4 acc[4][4];
        tile_gemm_t(vf, hf, acc);
#pragma unroll
        for (int j = 0; j < 4; ++j) {
            float* rp = out + (size_t)(rowbase + j * 16 + lr) * V_SZ + vbase + lg * 4;
#pragma unroll
            for (int i = 0; i < 4; ++i) {
                f32x4 v;
                v.x = acc[i][j].x - lsev[j];
                v.y = acc[i][j].y - lsev[j];
                v.z = acc[i][j].z - lsev[j];
                v.w = acc[i][j].w - lsev[j];
                *(f32x4*)(rp + i * 16) = v;
            }
        }
    };

    bf16x8 hfA[4][2], hfB[4][2];
    load_hfrag(hcat, y0, lg, lr, hfA);
    load_hfrag(hcat, y0 + 64, lg, lr, hfB);        // in flight during tile 0
    epilogue(hfA, y0);
    load_hfrag(hcat, y0 + 128, lg, lr, hfA);       // in flight during tile 1
    epilogue(hfB, y0 + 64);
    load_hfrag(hcat, y0 + 192, lg, lr, hfB);       // in flight during tile 2
    epilogue(hfA, y0 + 128);
    epilogue(hfB, y0 + 192);
}

// ---------------------------------------------------------------------------
extern "C" void kernel_launch(void* const* d_in, const int* in_sizes, int n_in,
                              void* d_out, int out_size, void* d_ws, size_t ws_size,
                              hipStream_t stream) {
    (void)in_sizes; (void)n_in; (void)out_size; (void)ws_size;
    const int*   inp   = (const int*)d_in[0];
    const float* we    = (const float*)d_in[1];
    const float* i2h1  = (const float*)d_in[2];
    const float* i2h2  = (const float*)d_in[3];
    const float* h2o   = (const float*)d_in[4];
    const float* bias  = (const float*)d_in[5];
    const float* hinit = (const float*)d_in[6];
    float* out = (float*)d_out;
    char* ws = (char*)d_ws;
    unsigned short* hcat_u = (unsigned short*)(ws);           //  262144 B
    unsigned short* h2oT_u = (unsigned short*)(ws + 262144);  // 4096000 B
    float*          Asum   = (float*)(ws + 4358144);          // 4096000 B
    float*          lse    = (float*)(ws + 8454144);          //    8192 B

    k_prep_rnn<<<157, 256, 0, stream>>>(inp, we, i2h1, i2h2, h2o, bias, hinit,
                                        hcat_u, h2oT_u);
    k_pass_a<<<dim3(NVT, 8), 256, 0, stream>>>(
        (const __bf16*)hcat_u, (const __bf16*)h2oT_u, Asum);
    k_lse<<<8, 256, 0, stream>>>(Asum, lse);
    k_pass_b<<<dim3(NVT, 8), 256, 0, stream>>>(
        (const __bf16*)hcat_u, (const __bf16*)h2oT_u, lse, out);
}

// Round 14
// 158.327 us; speedup vs baseline: 2.4141x; 1.0095x over previous
//
#include <hip/hip_runtime.h>

// Problem constants
#define V_SZ 32000
#define E_SZ 128
#define H_SZ 32
#define L_SZ 64
#define B_SZ 32
#define M_TOT 2048   // L*B rows
#define K2 64        // 2H
#define NVT 125      // V/256 col-slices
#define NPART 500    // sum-exp partials per row (125 xcol x 4 waves)

typedef __bf16 bf16x8 __attribute__((ext_vector_type(8)));
typedef float f32x4 __attribute__((ext_vector_type(4)));

__device__ __forceinline__ unsigned short f2bf(float f) {
    unsigned int u = __float_as_uint(f);
    u += 0x7FFFu + ((u >> 16) & 1u);   // round-to-nearest-even
    return (unsigned short)(u >> 16);
}

// ---------------------------------------------------------------------------
// Swapped-operand fragments (R12/R13-proven): vocab-as-M, hcat-rows-as-N.
// D: vocab = vbase + i*16 + lg*4 + reg, hrow = rowbase + j*16 + lr
// -> each lane's reg quad = 4 consecutive vocab of one output row.
// ---------------------------------------------------------------------------
__device__ __forceinline__ void load_vfrag(
    const __bf16* __restrict__ h2oT, int vbase, int lg, int lr,
    bf16x8 vf[4][2]) {
#pragma unroll
    for (int i = 0; i < 4; ++i) {
        const __bf16* vp = h2oT + (size_t)(vbase + i * 16 + lr) * K2 + lg * 8;
        vf[i][0] = *(const bf16x8*)(vp);
        vf[i][1] = *(const bf16x8*)(vp + 32);
    }
}

__device__ __forceinline__ void load_hfrag(
    const __bf16* __restrict__ hcat, int rowbase, int lg, int lr,
    bf16x8 hf[4][2]) {
#pragma unroll
    for (int j = 0; j < 4; ++j) {
        const __bf16* hp = hcat + (size_t)(rowbase + j * 16 + lr) * K2 + lg * 8;
        hf[j][0] = *(const bf16x8*)(hp);
        hf[j][1] = *(const bf16x8*)(hp + 32);
    }
}

__device__ __forceinline__ void tile_gemm_t(
    const bf16x8 vf[4][2], const bf16x8 hf[4][2], f32x4 acc[4][4]) {
#pragma unroll
    for (int i = 0; i < 4; ++i)
#pragma unroll
        for (int j = 0; j < 4; ++j) acc[i][j] = (f32x4){0.f, 0.f, 0.f, 0.f};
#pragma unroll
    for (int i = 0; i < 4; ++i)
#pragma unroll
        for (int j = 0; j < 4; ++j) {
            acc[i][j] = __builtin_amdgcn_mfma_f32_16x16x32_bf16(vf[i][0], hf[j][0], acc[i][j], 0, 0, 0);
            acc[i][j] = __builtin_amdgcn_mfma_f32_16x16x32_bf16(vf[i][1], hf[j][1], acc[i][j], 0, 0, 0);
        }
}

// ---------------------------------------------------------------------------
// Kernel 1: blocks 0..499  -> transpose+convert h2o -> h2oT (64 rows each;
//           500 blocks for full-GPU occupancy during the prep phase)
//           blocks 500..531 -> emb-GEMM into LDS + RNN recurrence
// ---------------------------------------------------------------------------
__global__ __launch_bounds__(256) void k_prep_rnn(
    const int* __restrict__ inp, const float* __restrict__ we,
    const float* __restrict__ i2h1, const float* __restrict__ i2h2,
    const float* __restrict__ h2o, const float* __restrict__ bias,
    const float* __restrict__ hinit,
    unsigned short* __restrict__ hcat_u, unsigned short* __restrict__ h2oT_u) {
    const int tid = threadIdx.x;
    const int p = blockIdx.x;
    if (p < 500) {
        // ---- h2o transpose: 64 vocab, 4 k-groups of 16 ----
        const int v = p * 64 + (tid & 63);         // [0,32000) exact
        const int kg = tid >> 6;                   // 0..3
        unsigned int* dst = (unsigned int*)(h2oT_u + (size_t)v * K2 + kg * 16);
#pragma unroll
        for (int kk = 0; kk < 16; kk += 2) {
            const int k = kg * 16 + kk;
            float a = h2o[(size_t)k * V_SZ + v];
            float b = h2o[(size_t)(k + 1) * V_SZ + v];
            dst[kk >> 1] = (unsigned int)f2bf(a) | ((unsigned int)f2bf(b) << 16);
        }
        return;
    }
    // ---- emb + RNN block (one direction, 2 batch rows) ----
    const int w2 = p - 500;                        // 0..31
    const int dir = w2 >> 4;
    const int bpair = w2 & 15;
    const float* W = dir ? i2h2 : i2h1;
    __shared__ float Xl[L_SZ * 2 * H_SZ];          // 16 KB: X[t][bb][j]
    {
        const int j = tid & 31, bb = (tid >> 5) & 1, to = tid >> 6;
        const int b = bpair * 2 + bb;
        const float bj = bias[j];
        for (int tt = 0; tt < 16; ++tt) {
            const int t = to * 16 + tt;
            const int idx = inp[t * B_SZ + b];
            const float* er = we + (size_t)idx * E_SZ;
            float acc = bj;
#pragma unroll
            for (int k0 = 0; k0 < E_SZ; k0 += 4) {
                f32x4 e4 = *(const f32x4*)(er + k0);
                acc += e4.x * W[(k0 + 0) * H_SZ + j];
                acc += e4.y * W[(k0 + 1) * H_SZ + j];
                acc += e4.z * W[(k0 + 2) * H_SZ + j];
                acc += e4.w * W[(k0 + 3) * H_SZ + j];
            }
            Xl[(t * 2 + bb) * H_SZ + j] = acc;
        }
    }
    __syncthreads();
    if (tid < 64) {
        const int lane = tid;
        const int bb = lane >> 5;
        const int b = bpair * 2 + bb;
        const int j = lane & 31;
        const int srcbase = lane & 32;
        float wh[H_SZ];
#pragma unroll
        for (int k = 0; k < H_SZ; ++k) wh[k] = W[(E_SZ + k) * H_SZ + j];
        float h = hinit[j];
        for (int step = 0; step < L_SZ; ++step) {
            const int tt = dir ? (L_SZ - 1 - step) : step;
            hcat_u[(tt * B_SZ + b) * K2 + dir * H_SZ + j] = f2bf(h);
            float a0 = Xl[(tt * 2 + bb) * H_SZ + j];
            float a1 = 0.f, a2 = 0.f, a3 = 0.f;
#pragma unroll
            for (int k = 0; k < H_SZ; k += 4) {
                a0 += __shfl(h, srcbase | k, 64) * wh[k];
                a1 += __shfl(h, srcbase | (k + 1), 64) * wh[k + 1];
                a2 += __shfl(h, srcbase | (k + 2), 64) * wh[k + 2];
                a3 += __shfl(h, srcbase | (k + 3), 64) * wh[k + 3];
            }
            float x2 = (a0 + a1) + (a2 + a3);
            float e = __expf(2.f * x2);            // tanh = 1 - 2/(e^{2x}+1)
            h = 1.f - 2.f * __builtin_amdgcn_rcpf(e + 1.f);
        }
    }
}

// ---------------------------------------------------------------------------
// Kernel 2 (pass A): grid (125,4), 8 row-tiles/block, zero LDS/barriers.
// vfrag loaded once; hfrag rolling double-buffer (fully unrolled) so tile
// t+1's loads overlap tile t's MFMA + exp/shfl. Partials -> Asum[pcol][row].
// ---------------------------------------------------------------------------
__global__ __launch_bounds__(256) void k_pass_a(
    const __bf16* __restrict__ hcat, const __bf16* __restrict__ h2oT,
    float* __restrict__ Asum) {
    const int tid = threadIdx.x;
    const int wave = tid >> 6, lane = tid & 63;
    const int lg = lane >> 4, lr = lane & 15;
    const int y0 = blockIdx.y * 512;               // 8 tiles x 64 rows
    const int vbase = blockIdx.x * 256 + wave * 64;
    const int pcol = blockIdx.x * 4 + wave;

    bf16x8 vf[4][2];
    load_vfrag(h2oT, vbase, lg, lr, vf);

    auto epilogue = [&](const bf16x8 hf[4][2], int rowbase) {
        f32x4 acc[4][4];
        tile_gemm_t(vf, hf, acc);
        float srow[4];
#pragma unroll
        for (int j = 0; j < 4; ++j) {
            float s = 0.f;
#pragma unroll
            for (int i = 0; i < 4; ++i)
#pragma unroll
                for (int r = 0; r < 4; ++r) s += __expf(acc[i][j][r]);
            srow[j] = s;
        }
#pragma unroll
        for (int j = 0; j < 4; ++j) {
            srow[j] += __shfl_xor(srow[j], 16, 64);
            srow[j] += __shfl_xor(srow[j], 32, 64);
        }
        if (lane < 16) {
#pragma unroll
            for (int j = 0; j < 4; ++j)
                Asum[(size_t)pcol * M_TOT + rowbase + j * 16 + lane] = srow[j];
        }
    };

    bf16x8 hfA[4][2], hfB[4][2];
    load_hfrag(hcat, y0, lg, lr, hfA);
#pragma unroll
    for (int t = 0; t < 8; ++t) {                  // fully unrolled: static idx
        if (t & 1) {
            if (t < 7) load_hfrag(hcat, y0 + (t + 1) * 64, lg, lr, hfA);
            epilogue(hfB, y0 + t * 64);
        } else {
            if (t < 7) load_hfrag(hcat, y0 + (t + 1) * 64, lg, lr, hfB);
            epilogue(hfA, y0 + t * 64);
        }
    }
}

// ---------------------------------------------------------------------------
// Kernel 3: reduce 500 partials -> lse[row] = log(sum). Coalesced (lane=row).
// ---------------------------------------------------------------------------
__global__ __launch_bounds__(256) void k_lse(
    const float* __restrict__ Asum, float* __restrict__ lse) {
    const int row = blockIdx.x * 256 + threadIdx.x;
    float s = 0.f;
    for (int i = 0; i < NPART; ++i) s += Asum[(size_t)i * M_TOT + row];
    lse[row] = logf(s);
}

// ---------------------------------------------------------------------------
// Kernel 4 (pass B): grid (125,4), 8 row-tiles/block, zero LDS/barriers.
// vfrag loaded once; hfrag rolling double-buffer; direct f32x4 stores from
// regs (lanes {l,l+16,l+32,l+48} form 64B row segments).
// ---------------------------------------------------------------------------
__global__ __launch_bounds__(256) void k_pass_b(
    const __bf16* __restrict__ hcat, const __bf16* __restrict__ h2oT,
    const float* __restrict__ lse, float* __restrict__ out) {
    const int tid = threadIdx.x;
    const int wave = tid >> 6, lane = tid & 63;
    const int lg = lane >> 4, lr = lane & 15;
    const int y0 = blockIdx.y * 512;               // 8 tiles x 64 rows
    const int vbase = blockIdx.x * 256 + wave * 64;

    bf16x8 vf[4][2];
    load_vfrag(h2oT, vbase, lg, lr, vf);

    auto epilogue = [&](const bf16x8 hf[4][2], int rowbase) {
        float lsev[4];
#pragma unroll
        for (int j = 0; j < 4; ++j)
            lsev[j] = lse[rowbase + j * 16 + lr];
        f32x4 acc[4][4];
        tile_gemm_t(vf, hf, acc);
#pragma unroll
        for (int j = 0; j < 4; ++j) {
            float* rp = out + (size_t)(rowbase + j * 16 + lr) * V_SZ + vbase + lg * 4;
#pragma unroll
            for (int i = 0; i < 4; ++i) {
                f32x4 v;
                v.x = acc[i][j].x - lsev[j];
                v.y = acc[i][j].y - lsev[j];
                v.z = acc[i][j].z - lsev[j];
                v.w = acc[i][j].w - lsev[j];
                *(f32x4*)(rp + i * 16) = v;
            }
        }
    };

    bf16x8 hfA[4][2], hfB[4][2];
    load_hfrag(hcat, y0, lg, lr, hfA);
#pragma unroll
    for (int t = 0; t < 8; ++t) {                  // fully unrolled: static idx
        if (t & 1) {
            if (t < 7) load_hfrag(hcat, y0 + (t + 1) * 64, lg, lr, hfA);
            epilogue(hfB, y0 + t * 64);
        } else {
            if (t < 7) load_hfrag(hcat, y0 + (t + 1) * 64, lg, lr, hfB);
            epilogue(hfA, y0 + t * 64);
        }
    }
}

// ---------------------------------------------------------------------------
extern "C" void kernel_launch(void* const* d_in, const int* in_sizes, int n_in,
                              void* d_out, int out_size, void* d_ws, size_t ws_size,
                              hipStream_t stream) {
    (void)in_sizes; (void)n_in; (void)out_size; (void)ws_size;
    const int*   inp   = (const int*)d_in[0];
    const float* we    = (const float*)d_in[1];
    const float* i2h1  = (const float*)d_in[2];
    const float* i2h2  = (const float*)d_in[3];
    const float* h2o   = (const float*)d_in[4];
    const float* bias  = (const float*)d_in[5];
    const float* hinit = (const float*)d_in[6];
    float* out = (float*)d_out;
    char* ws = (char*)d_ws;
    unsigned short* hcat_u = (unsigned short*)(ws);           //  262144 B
    unsigned short* h2oT_u = (unsigned short*)(ws + 262144);  // 4096000 B
    float*          Asum   = (float*)(ws + 4358144);          // 4096000 B
    float*          lse    = (float*)(ws + 8454144);          //    8192 B

    k_prep_rnn<<<532, 256, 0, stream>>>(inp, we, i2h1, i2h2, h2o, bias, hinit,
                                        hcat_u, h2oT_u);
    k_pass_a<<<dim3(NVT, 4), 256, 0, stream>>>(
        (const __bf16*)hcat_u, (const __bf16*)h2oT_u, Asum);
    k_lse<<<8, 256, 0, stream>>>(Asum, lse);
    k_pass_b<<<dim3(NVT, 4), 256, 0, stream>>>(
        (const __bf16*)hcat_u, (const __bf16*)h2oT_u, lse, out);
}

// Round 15
// 154.094 us; speedup vs baseline: 2.4804x; 1.0275x over previous
//
#include <hip/hip_runtime.h>
#include <hip/hip_cooperative_groups.h>

namespace cg = cooperative_groups;

// Problem constants
#define V_SZ 32000
#define E_SZ 128
#define H_SZ 32
#define L_SZ 64
#define B_SZ 32
#define M_TOT 2048   // L*B rows
#define K2 64        // 2H
#define NVT 125      // V/256 col-slices

typedef __bf16 bf16x8 __attribute__((ext_vector_type(8)));
typedef float f32x4 __attribute__((ext_vector_type(4)));

__device__ __forceinline__ unsigned short f2bf(float f) {
    unsigned int u = __float_as_uint(f);
    u += 0x7FFFu + ((u >> 16) & 1u);   // round-to-nearest-even
    return (unsigned short)(u >> 16);
}

// ---------------------------------------------------------------------------
// Swapped-operand fragments (R12-R14 proven): vocab-as-M, hcat-rows-as-N.
// D: vocab = vbase + i*16 + lg*4 + reg, hrow = rowbase + j*16 + lr
// -> each lane's reg quad = 4 consecutive vocab of one output row.
// ---------------------------------------------------------------------------
__device__ __forceinline__ void load_vfrag(
    const __bf16* __restrict__ h2oT, int vbase, int lg, int lr,
    bf16x8 vf[4][2]) {
#pragma unroll
    for (int i = 0; i < 4; ++i) {
        const __bf16* vp = h2oT + (size_t)(vbase + i * 16 + lr) * K2 + lg * 8;
        vf[i][0] = *(const bf16x8*)(vp);
        vf[i][1] = *(const bf16x8*)(vp + 32);
    }
}

__device__ __forceinline__ void load_hfrag(
    const __bf16* __restrict__ hcat, int rowbase, int lg, int lr,
    bf16x8 hf[4][2]) {
#pragma unroll
    for (int j = 0; j < 4; ++j) {
        const __bf16* hp = hcat + (size_t)(rowbase + j * 16 + lr) * K2 + lg * 8;
        hf[j][0] = *(const bf16x8*)(hp);
        hf[j][1] = *(const bf16x8*)(hp + 32);
    }
}

__device__ __forceinline__ void tile_gemm_t(
    const bf16x8 vf[4][2], const bf16x8 hf[4][2], f32x4 acc[4][4]) {
#pragma unroll
    for (int i = 0; i < 4; ++i)
#pragma unroll
        for (int j = 0; j < 4; ++j) acc[i][j] = (f32x4){0.f, 0.f, 0.f, 0.f};
#pragma unroll
    for (int i = 0; i < 4; ++i)
#pragma unroll
        for (int j = 0; j < 4; ++j) {
            acc[i][j] = __builtin_amdgcn_mfma_f32_16x16x32_bf16(vf[i][0], hf[j][0], acc[i][j], 0, 0, 0);
            acc[i][j] = __builtin_amdgcn_mfma_f32_16x16x32_bf16(vf[i][1], hf[j][1], acc[i][j], 0, 0, 0);
        }
}

// 8-tile sweep with rolling double-buffered hfrag (R13/R14-proven pipeline).
template <typename EP>
__device__ __forceinline__ void sweep8(
    const __bf16* __restrict__ hcat, int y0, int lg, int lr, EP&& ep) {
    bf16x8 hfA[4][2], hfB[4][2];
    load_hfrag(hcat, y0, lg, lr, hfA);
#pragma unroll
    for (int t = 0; t < 8; ++t) {                  // fully unrolled: static idx
        if (t & 1) {
            if (t < 7) load_hfrag(hcat, y0 + (t + 1) * 64, lg, lr, hfA);
            ep(hfB, y0 + t * 64);
        } else {
            if (t < 7) load_hfrag(hcat, y0 + (t + 1) * 64, lg, lr, hfB);
            ep(hfA, y0 + t * 64);
        }
    }
}

// Phase-A epilogue: sum-exp + 16-lane reduce + atomicAdd into S[row].
struct EpA {
    const bf16x8 (*vf)[2];
    float* S;
    int lane, lg, lr;
    __device__ __forceinline__ void operator()(const bf16x8 hf[4][2], int rowbase) const {
        f32x4 acc[4][4];
        tile_gemm_t((const bf16x8(*)[2])vf, hf, acc);
        float srow[4];
#pragma unroll
        for (int j = 0; j < 4; ++j) {
            float s = 0.f;
#pragma unroll
            for (int i = 0; i < 4; ++i)
#pragma unroll
                for (int r = 0; r < 4; ++r) s += __expf(acc[i][j][r]);
            srow[j] = s;
        }
#pragma unroll
        for (int j = 0; j < 4; ++j) {
            srow[j] += __shfl_xor(srow[j], 16, 64);
            srow[j] += __shfl_xor(srow[j], 32, 64);
        }
        if (lane < 16) {
#pragma unroll
            for (int j = 0; j < 4; ++j)
                atomicAdd(&S[rowbase + j * 16 + lane], srow[j]);
        }
    }
};

// Phase-B epilogue: lse from S, recompute, direct f32x4 stores.
struct EpB {
    const bf16x8 (*vf)[2];
    const float* S;
    float* out;
    int vbase, lg, lr;
    __device__ __forceinline__ void operator()(const bf16x8 hf[4][2], int rowbase) const {
        float lsev[4];
#pragma unroll
        for (int j = 0; j < 4; ++j)
            lsev[j] = logf(S[rowbase + j * 16 + lr]);
        f32x4 acc[4][4];
        tile_gemm_t((const bf16x8(*)[2])vf, hf, acc);
#pragma unroll
        for (int j = 0; j < 4; ++j) {
            float* rp = out + (size_t)(rowbase + j * 16 + lr) * V_SZ + vbase + lg * 4;
#pragma unroll
            for (int i = 0; i < 4; ++i) {
                f32x4 v;
                v.x = acc[i][j].x - lsev[j];
                v.y = acc[i][j].y - lsev[j];
                v.z = acc[i][j].z - lsev[j];
                v.w = acc[i][j].w - lsev[j];
                *(f32x4*)(rp + i * 16) = v;
            }
        }
    }
};

// ---------------------------------------------------------------------------
// Kernel 1: blocks 0..499  -> transpose+convert h2o -> h2oT (64 rows each);
//           block 0 also zeroes S.  blocks 500..531 -> emb-GEMM + RNN.
// ---------------------------------------------------------------------------
__global__ __launch_bounds__(256) void k_prep_rnn(
    const int* __restrict__ inp, const float* __restrict__ we,
    const float* __restrict__ i2h1, const float* __restrict__ i2h2,
    const float* __restrict__ h2o, const float* __restrict__ bias,
    const float* __restrict__ hinit,
    unsigned short* __restrict__ hcat_u, unsigned short* __restrict__ h2oT_u,
    float* __restrict__ S) {
    const int tid = threadIdx.x;
    const int p = blockIdx.x;
    if (p < 500) {
        if (p == 0) {
#pragma unroll
            for (int i = tid; i < M_TOT; i += 256) S[i] = 0.f;
        }
        const int v = p * 64 + (tid & 63);         // [0,32000) exact
        const int kg = tid >> 6;                   // 0..3
        unsigned int* dst = (unsigned int*)(h2oT_u + (size_t)v * K2 + kg * 16);
#pragma unroll
        for (int kk = 0; kk < 16; kk += 2) {
            const int k = kg * 16 + kk;
            float a = h2o[(size_t)k * V_SZ + v];
            float b = h2o[(size_t)(k + 1) * V_SZ + v];
            dst[kk >> 1] = (unsigned int)f2bf(a) | ((unsigned int)f2bf(b) << 16);
        }
        return;
    }
    // ---- emb + RNN block (one direction, 2 batch rows) ----
    const int w2 = p - 500;                        // 0..31
    const int dir = w2 >> 4;
    const int bpair = w2 & 15;
    const float* W = dir ? i2h2 : i2h1;
    __shared__ float Xl[L_SZ * 2 * H_SZ];          // 16 KB: X[t][bb][j]
    {
        const int j = tid & 31, bb = (tid >> 5) & 1, to = tid >> 6;
        const int b = bpair * 2 + bb;
        const float bj = bias[j];
        for (int tt = 0; tt < 16; ++tt) {
            const int t = to * 16 + tt;
            const int idx = inp[t * B_SZ + b];
            const float* er = we + (size_t)idx * E_SZ;
            float acc = bj;
#pragma unroll
            for (int k0 = 0; k0 < E_SZ; k0 += 4) {
                f32x4 e4 = *(const f32x4*)(er + k0);
                acc += e4.x * W[(k0 + 0) * H_SZ + j];
                acc += e4.y * W[(k0 + 1) * H_SZ + j];
                acc += e4.z * W[(k0 + 2) * H_SZ + j];
                acc += e4.w * W[(k0 + 3) * H_SZ + j];
            }
            Xl[(t * 2 + bb) * H_SZ + j] = acc;
        }
    }
    __syncthreads();
    if (tid < 64) {
        const int lane = tid;
        const int bb = lane >> 5;
        const int b = bpair * 2 + bb;
        const int j = lane & 31;
        const int srcbase = lane & 32;
        float wh[H_SZ];
#pragma unroll
        for (int k = 0; k < H_SZ; ++k) wh[k] = W[(E_SZ + k) * H_SZ + j];
        float h = hinit[j];
        for (int step = 0; step < L_SZ; ++step) {
            const int tt = dir ? (L_SZ - 1 - step) : step;
            hcat_u[(tt * B_SZ + b) * K2 + dir * H_SZ + j] = f2bf(h);
            float a0 = Xl[(tt * 2 + bb) * H_SZ + j];
            float a1 = 0.f, a2 = 0.f, a3 = 0.f;
#pragma unroll
            for (int k = 0; k < H_SZ; k += 4) {
                a0 += __shfl(h, srcbase | k, 64) * wh[k];
                a1 += __shfl(h, srcbase | (k + 1), 64) * wh[k + 1];
                a2 += __shfl(h, srcbase | (k + 2), 64) * wh[k + 2];
                a3 += __shfl(h, srcbase | (k + 3), 64) * wh[k + 3];
            }
            float x2 = (a0 + a1) + (a2 + a3);
            float e = __expf(2.f * x2);            // tanh = 1 - 2/(e^{2x}+1)
            h = 1.f - 2.f * __builtin_amdgcn_rcpf(e + 1.f);
        }
    }
}

// ---------------------------------------------------------------------------
// Fused cooperative kernel: 500 blocks (unit = xcol x ygroup), phase A
// (sum-exp + atomic S) -> grid.sync -> phase B (recompute + store), with
// vfrag register-resident across BOTH phases. Work structure identical to
// the proven R14 split kernels.
// ---------------------------------------------------------------------------
__global__ __launch_bounds__(256) void k_fused(
    const unsigned short* __restrict__ hcat_u,
    const unsigned short* __restrict__ h2oT_u,
    float* __restrict__ S, float* __restrict__ out) {
    cg::grid_group gg = cg::this_grid();
    const int tid = threadIdx.x;
    const int wave = tid >> 6, lane = tid & 63;
    const int lg = lane >> 4, lr = lane & 15;
    const int xcol = blockIdx.x >> 2;
    const int y0 = (blockIdx.x & 3) * 512;         // 8 tiles x 64 rows
    const int vbase = xcol * 256 + wave * 64;
    const __bf16* hcat = (const __bf16*)hcat_u;
    const __bf16* h2oT = (const __bf16*)h2oT_u;

    bf16x8 vf[4][2];
    load_vfrag(h2oT, vbase, lg, lr, vf);

    EpA epa{vf, S, lane, lg, lr};
    sweep8(hcat, y0, lg, lr, epa);

    __threadfence();
    gg.sync();

    EpB epb{vf, S, out, vbase, lg, lr};
    sweep8(hcat, y0, lg, lr, epb);
}

// ---------------------------------------------------------------------------
// Fallback split kernels (same epilogues, same geometry)
// ---------------------------------------------------------------------------
__global__ __launch_bounds__(256) void k_pass_a(
    const __bf16* __restrict__ hcat, const __bf16* __restrict__ h2oT,
    float* __restrict__ S) {
    const int tid = threadIdx.x;
    const int wave = tid >> 6, lane = tid & 63;
    const int lg = lane >> 4, lr = lane & 15;
    const int y0 = blockIdx.y * 512;
    const int vbase = blockIdx.x * 256 + wave * 64;
    bf16x8 vf[4][2];
    load_vfrag(h2oT, vbase, lg, lr, vf);
    EpA epa{vf, S, lane, lg, lr};
    sweep8(hcat, y0, lg, lr, epa);
}

__global__ __launch_bounds__(256) void k_pass_b(
    const __bf16* __restrict__ hcat, const __bf16* __restrict__ h2oT,
    const float* __restrict__ S, float* __restrict__ out) {
    const int tid = threadIdx.x;
    const int wave = tid >> 6, lane = tid & 63;
    const int lg = lane >> 4, lr = lane & 15;
    const int y0 = blockIdx.y * 512;
    const int vbase = blockIdx.x * 256 + wave * 64;
    bf16x8 vf[4][2];
    load_vfrag(h2oT, vbase, lg, lr, vf);
    EpB epb{vf, S, out, vbase, lg, lr};
    sweep8(hcat, y0, lg, lr, epb);
}

// ---------------------------------------------------------------------------
extern "C" void kernel_launch(void* const* d_in, const int* in_sizes, int n_in,
                              void* d_out, int out_size, void* d_ws, size_t ws_size,
                              hipStream_t stream) {
    (void)in_sizes; (void)n_in; (void)out_size; (void)ws_size;
    const int*   inp   = (const int*)d_in[0];
    const float* we    = (const float*)d_in[1];
    const float* i2h1  = (const float*)d_in[2];
    const float* i2h2  = (const float*)d_in[3];
    const float* h2o   = (const float*)d_in[4];
    const float* bias  = (const float*)d_in[5];
    const float* hinit = (const float*)d_in[6];
    float* out = (float*)d_out;
    char* ws = (char*)d_ws;
    unsigned short* hcat_u = (unsigned short*)(ws);           //  262144 B
    unsigned short* h2oT_u = (unsigned short*)(ws + 262144);  // 4096000 B
    float*          S      = (float*)(ws + 4358144);          //    8192 B

    k_prep_rnn<<<532, 256, 0, stream>>>(inp, we, i2h1, i2h2, h2o, bias, hinit,
                                        hcat_u, h2oT_u, S);

    hipError_t e = hipErrorUnknown;
    int occ = 0;
    if (hipOccupancyMaxActiveBlocksPerMultiprocessor(&occ, k_fused, 256, 0)
            == hipSuccess && occ * 256 >= 500) {
        void* args[] = {(void*)&hcat_u, (void*)&h2oT_u, (void*)&S, (void*)&out};
        e = hipLaunchCooperativeKernel((void*)k_fused, dim3(500), dim3(256),
                                       args, 0, stream);
    }
    if (e != hipSuccess) {
        k_pass_a<<<dim3(NVT, 4), 256, 0, stream>>>(
            (const __bf16*)hcat_u, (const __bf16*)h2oT_u, S);
        k_pass_b<<<dim3(NVT, 4), 256, 0, stream>>>(
            (const __bf16*)hcat_u, (const __bf16*)h2oT_u, S, out);
    }
}